// Round 1
// baseline (58727.466 us; speedup 1.0000x reference)
//
#include <hip/hip_runtime.h>

#define Bn 64
#define Tn 2048
#define In 128
#define Hn 256

__device__ __forceinline__ float fast_sigmoid(float x) {
    return 1.0f / (1.0f + __expf(-x));
}
__device__ __forceinline__ float fast_tanh(float x) {
    // tanh(x) = 2*sigmoid(2x) - 1 ; saturates correctly for large |x|
    return 2.0f / (1.0f + __expf(-2.0f * x)) - 1.0f;
}

// One workgroup per batch chain. 256 threads; thread j owns hidden column j.
// h0/h1/cur live in LDS; weights stream from (XCD-resident) L2, coalesced
// across lanes via the [k*H + j] layout.
__global__ __launch_bounds__(256, 1)
void alphat_rnn_kernel(const float* __restrict__ X,
                       const float* __restrict__ Wih0, const float* __restrict__ Whh0,
                       const float* __restrict__ bh0,  const float* __restrict__ Wax0,
                       const float* __restrict__ Wah0, const float* __restrict__ ba0,
                       const float* __restrict__ Wih1, const float* __restrict__ Whh1,
                       const float* __restrict__ bh1,  const float* __restrict__ Wax1,
                       const float* __restrict__ Wah1, const float* __restrict__ ba1,
                       float* __restrict__ out, float* __restrict__ hfin)
{
    __shared__ float xrow[In];
    __shared__ float h0[Hn];
    __shared__ float h1[Hn];
    __shared__ float cur[Hn];

    const int b = blockIdx.x;
    const int j = threadIdx.x;

    const float bias_h0 = bh0[j];
    const float bias_a0 = ba0[j];
    const float bias_h1 = bh1[j];
    const float bias_a1 = ba1[j];

    h0[j] = 0.0f;
    h1[j] = 0.0f;

    const float* __restrict__ xbase = X + (size_t)b * Tn * In;
    float* __restrict__ obase = out + (size_t)b * Tn * Hn;

    float hn0 = 0.0f;  // register copies of h0[j], h1[j]
    float hn1 = 0.0f;

    for (int t = 0; t < Tn; ++t) {
        // stage this timestep's input row
        if (j < In) xrow[j] = xbase[t * In + j];
        __syncthreads();  // SYNC_A: xrow ready; prior-iter h0/h1 writes visible

        // ---------- layer 0 ----------
        float aU = bias_h0;
        float aA = bias_a0;
        #pragma unroll 4
        for (int k = 0; k < In; k += 4) {
            const float4 xv = *reinterpret_cast<const float4*>(&xrow[k]);
            aU += xv.x * Wih0[(k + 0) * Hn + j];  aA += xv.x * Wax0[(k + 0) * Hn + j];
            aU += xv.y * Wih0[(k + 1) * Hn + j];  aA += xv.y * Wax0[(k + 1) * Hn + j];
            aU += xv.z * Wih0[(k + 2) * Hn + j];  aA += xv.z * Wax0[(k + 2) * Hn + j];
            aU += xv.w * Wih0[(k + 3) * Hn + j];  aA += xv.w * Wax0[(k + 3) * Hn + j];
        }
        #pragma unroll 4
        for (int k = 0; k < Hn; k += 4) {
            const float4 hv = *reinterpret_cast<const float4*>(&h0[k]);
            aU += hv.x * Whh0[(k + 0) * Hn + j];  aA += hv.x * Wah0[(k + 0) * Hn + j];
            aU += hv.y * Whh0[(k + 1) * Hn + j];  aA += hv.y * Wah0[(k + 1) * Hn + j];
            aU += hv.z * Whh0[(k + 2) * Hn + j];  aA += hv.z * Wah0[(k + 2) * Hn + j];
            aU += hv.w * Whh0[(k + 3) * Hn + j];  aA += hv.w * Wah0[(k + 3) * Hn + j];
        }
        {
            const float cand  = fast_tanh(aU);
            const float alpha = fast_sigmoid(aA);
            hn0 = alpha * cand + (1.0f - alpha) * hn0;
        }
        cur[j] = hn0;
        __syncthreads();  // SYNC_B: cur ready; all h0 reads of this step done
        h0[j] = hn0;      // safe: nobody reads h0 until after next SYNC_A

        // ---------- layer 1 ----------
        float aU1 = bias_h1;
        float aA1 = bias_a1;
        #pragma unroll 4
        for (int k = 0; k < Hn; k += 4) {
            const float4 cv = *reinterpret_cast<const float4*>(&cur[k]);
            aU1 += cv.x * Wih1[(k + 0) * Hn + j];  aA1 += cv.x * Wax1[(k + 0) * Hn + j];
            aU1 += cv.y * Wih1[(k + 1) * Hn + j];  aA1 += cv.y * Wax1[(k + 1) * Hn + j];
            aU1 += cv.z * Wih1[(k + 2) * Hn + j];  aA1 += cv.z * Wax1[(k + 2) * Hn + j];
            aU1 += cv.w * Wih1[(k + 3) * Hn + j];  aA1 += cv.w * Wax1[(k + 3) * Hn + j];
        }
        #pragma unroll 4
        for (int k = 0; k < Hn; k += 4) {
            const float4 hv = *reinterpret_cast<const float4*>(&h1[k]);
            aU1 += hv.x * Whh1[(k + 0) * Hn + j];  aA1 += hv.x * Wah1[(k + 0) * Hn + j];
            aU1 += hv.y * Whh1[(k + 1) * Hn + j];  aA1 += hv.y * Wah1[(k + 1) * Hn + j];
            aU1 += hv.z * Whh1[(k + 2) * Hn + j];  aA1 += hv.z * Wah1[(k + 2) * Hn + j];
            aU1 += hv.w * Whh1[(k + 3) * Hn + j];  aA1 += hv.w * Wah1[(k + 3) * Hn + j];
        }
        {
            const float cand  = fast_tanh(aU1);
            const float alpha = fast_sigmoid(aA1);
            hn1 = alpha * cand + (1.0f - alpha) * hn1;
        }
        obase[t * Hn + j] = hn1;
        __syncthreads();  // SYNC_C: all h1/cur reads of this step done
        h1[j] = hn1;      // visible to next step after its SYNC_A
    }

    // h_final: [L, B, H] appended after outputs
    hfin[(size_t)0 * Bn * Hn + b * Hn + j] = hn0;
    hfin[(size_t)1 * Bn * Hn + b * Hn + j] = hn1;
}

extern "C" void kernel_launch(void* const* d_in, const int* in_sizes, int n_in,
                              void* d_out, int out_size, void* d_ws, size_t ws_size,
                              hipStream_t stream) {
    const float* X    = (const float*)d_in[0];
    const float* Wih0 = (const float*)d_in[1];
    const float* Whh0 = (const float*)d_in[2];
    const float* bh0  = (const float*)d_in[3];
    const float* Wax0 = (const float*)d_in[4];
    const float* Wah0 = (const float*)d_in[5];
    const float* ba0  = (const float*)d_in[6];
    const float* Wih1 = (const float*)d_in[7];
    const float* Whh1 = (const float*)d_in[8];
    const float* bh1  = (const float*)d_in[9];
    const float* Wax1 = (const float*)d_in[10];
    const float* Wah1 = (const float*)d_in[11];
    const float* ba1  = (const float*)d_in[12];

    float* out  = (float*)d_out;
    float* hfin = out + (size_t)Bn * Tn * Hn;

    alphat_rnn_kernel<<<dim3(Bn), dim3(Hn), 0, stream>>>(
        X, Wih0, Whh0, bh0, Wax0, Wah0, ba0,
        Wih1, Whh1, bh1, Wax1, Wah1, ba1, out, hfin);
}

// Round 2
// 4471.515 us; speedup vs baseline: 13.1337x; 13.1337x over previous
//
#include <hip/hip_runtime.h>

#define Bn 64
#define Tn 2048
#define In 128
#define Hn 256
#define RS 512  // row stride in f16 elements for pre/out rows (1024 B)

typedef _Float16 h2 __attribute__((ext_vector_type(2)));

__device__ __forceinline__ float fast_sigmoid(float x) {
    return 1.0f / (1.0f + __expf(-x));
}
__device__ __forceinline__ float fast_tanh(float x) {
    return 2.0f / (1.0f + __expf(-2.0f * x)) - 1.0f;
}
__device__ __forceinline__ float dot2(h2 a, h2 b, float c) {
    return __builtin_amdgcn_fdot2(a, b, c, false);
}
__device__ __forceinline__ h2 bc2(float f) {
    return __builtin_bit_cast(h2, f);
}

// ---------------------------------------------------------------------------
// K1: pre0[m][512] (f16, in d_out) = X[m][0:128] @ [Wih0 | Wax0] + [bh0 | ba0]
// grid (Mtiles=2048, 2), block 256. M-tile 64 rows. s=0 -> U half, s=1 -> A.
// ---------------------------------------------------------------------------
__global__ void gemm_x_kernel(const float* __restrict__ X,
                              const float* __restrict__ Wih0, const float* __restrict__ bh0,
                              const float* __restrict__ Wax0, const float* __restrict__ ba0,
                              _Float16* __restrict__ pre)
{
    __shared__ __align__(16) float Xs[64 * In];  // 32 KB
    const int m0 = blockIdx.x * 64;
    const int s  = blockIdx.y;
    const float* __restrict__ W    = s ? Wax0 : Wih0;
    const float* __restrict__ bias = s ? ba0  : bh0;

    // stage X tile: 64 rows x 128 = contiguous 8192 floats
    {
        const float4* __restrict__ src = reinterpret_cast<const float4*>(X + (size_t)m0 * In);
        float4* __restrict__ dst = reinterpret_cast<float4*>(Xs);
        #pragma unroll
        for (int i = 0; i < 8; ++i) dst[threadIdx.x + 256 * i] = src[threadIdx.x + 256 * i];
    }
    __syncthreads();

    const int c  = threadIdx.x & 63;   // base col
    const int rg = threadIdx.x >> 6;   // row group (16 rows)
    const int mr = rg * 16;

    float acc[16][4];
    #pragma unroll
    for (int u = 0; u < 4; ++u) {
        const float bv = bias[c + 64 * u];
        #pragma unroll
        for (int r = 0; r < 16; ++r) acc[r][u] = bv;
    }

    const float4* __restrict__ Xs4 = reinterpret_cast<const float4*>(Xs);
    #pragma unroll 4
    for (int kc = 0; kc < 32; ++kc) {
        float wv[4][4];
        #pragma unroll
        for (int kk = 0; kk < 4; ++kk)
            #pragma unroll
            for (int u = 0; u < 4; ++u)
                wv[kk][u] = W[(size_t)(4 * kc + kk) * Hn + c + 64 * u];
        #pragma unroll
        for (int r = 0; r < 16; ++r) {
            const float4 xv = Xs4[(mr + r) * 32 + kc];
            #pragma unroll
            for (int u = 0; u < 4; ++u)
                acc[r][u] += xv.x * wv[0][u] + xv.y * wv[1][u] + xv.z * wv[2][u] + xv.w * wv[3][u];
        }
    }

    #pragma unroll
    for (int r = 0; r < 16; ++r)
        #pragma unroll
        for (int u = 0; u < 4; ++u)
            pre[(size_t)(m0 + mr + r) * RS + s * Hn + c + 64 * u] = (_Float16)acc[r][u];
}

// ---------------------------------------------------------------------------
// K3: pre1[m][512] (f16, in d_out, in-place) = h0[m][0:256](f16, bytes 0..511
// of same rows) @ [Wih1 | Wax1] + [bh1 | ba1].  grid 4096, block 256,
// M-tile 32 rows. Tile read into LDS BEFORE overwriting the rows.
// ---------------------------------------------------------------------------
__global__ void gemm_h_kernel(_Float16* __restrict__ pre,
                              const float* __restrict__ Wih1, const float* __restrict__ bh1,
                              const float* __restrict__ Wax1, const float* __restrict__ ba1)
{
    __shared__ __align__(16) _Float16 Hs[32 * Hn];  // 16 KB
    const int m0 = blockIdx.x * 32;

    // stage h0 tile: 32 rows x 256 f16 (512 B per row at stride 1024 B)
    {
        float4* __restrict__ dst = reinterpret_cast<float4*>(Hs);
        #pragma unroll
        for (int q = 0; q < 4; ++q) {
            const int id  = threadIdx.x + 256 * q;   // 0..1023 chunks of 16B
            const int row = id >> 5;
            const int off = id & 31;
            const float4* __restrict__ src =
                reinterpret_cast<const float4*>(pre + (size_t)(m0 + row) * RS);
            dst[row * 32 + off] = src[off];
        }
    }
    __syncthreads();

    const int c  = threadIdx.x & 63;
    const int rg = threadIdx.x >> 6;
    const int mr = rg * 8;

    const float* Wp[8];
    float acc[8][8];
    #pragma unroll
    for (int u = 0; u < 8; ++u) {
        const int colu = c + 64 * u;
        const float bv = (colu < Hn) ? bh1[colu] : ba1[colu - Hn];
        Wp[u] = (colu < Hn) ? (Wih1 + colu) : (Wax1 + (colu - Hn));
        #pragma unroll
        for (int r = 0; r < 8; ++r) acc[r][u] = bv;
    }

    const float2* __restrict__ Hs2 = reinterpret_cast<const float2*>(Hs);
    #pragma unroll 2
    for (int kc = 0; kc < 64; ++kc) {   // 4 k's per iter
        float wv[4][8];
        #pragma unroll
        for (int kk = 0; kk < 4; ++kk)
            #pragma unroll
            for (int u = 0; u < 8; ++u)
                wv[kk][u] = Wp[u][(size_t)(4 * kc + kk) * Hn];
        #pragma unroll
        for (int r = 0; r < 8; ++r) {
            const float2 q = Hs2[(mr + r) * 64 + kc];
            const h2 p0 = bc2(q.x), p1 = bc2(q.y);
            const float f0 = (float)p0.x, f1 = (float)p0.y, f2 = (float)p1.x, f3 = (float)p1.y;
            #pragma unroll
            for (int u = 0; u < 8; ++u)
                acc[r][u] += f0 * wv[0][u] + f1 * wv[1][u] + f2 * wv[2][u] + f3 * wv[3][u];
        }
    }

    #pragma unroll
    for (int r = 0; r < 8; ++r)
        #pragma unroll
        for (int u = 0; u < 8; ++u)
            pre[(size_t)(m0 + mr + r) * RS + c + 64 * u] = (_Float16)acc[r][u];
}

// ---------------------------------------------------------------------------
// Scan kernel (used for both layers). 64 blocks x 512 threads.
// tid<256: U-column j (weights Whh[:,j] in VGPRs, f16x2-packed);
// tid>=256: A-column j (Wah[:,j]).  h broadcast via LDS (f16).
// writeF32=0: write h[t] f16 into bytes 0..511 of row t (over consumed pre).
// writeF32=1: write fp32 output row in place of pre row (read-before-write
//             separated by barrier / row distinction).
// ---------------------------------------------------------------------------
__global__ __launch_bounds__(512, 2)
void scan_kernel(_Float16* __restrict__ pre,
                 const float* __restrict__ WU, const float* __restrict__ WA,
                 float* __restrict__ outf, float* __restrict__ hfin, int writeF32)
{
    __shared__ __align__(16) _Float16 hbuf[Hn];
    __shared__ float alpha_s[Hn];

    const int b    = blockIdx.x;
    const int tid  = threadIdx.x;
    const int half = tid >> 8;       // wave-uniform
    const int j    = tid & 255;

    // ---- load recurrent weight column into registers, packed f16x2 ----
    const float* __restrict__ Wcol = (half ? WA : WU) + j;
    h2 wreg[128];
    #pragma unroll
    for (int k2 = 0; k2 < 128; ++k2) {
        const float w0 = Wcol[(size_t)(2 * k2) * Hn];
        const float w1 = Wcol[(size_t)(2 * k2 + 1) * Hn];
        h2 p; p.x = (_Float16)w0; p.y = (_Float16)w1;
        wreg[k2] = p;
    }

    if (tid < Hn) hbuf[tid] = (_Float16)0.0f;
    float hprev = 0.0f;

    _Float16* __restrict__ rowbase = pre + (size_t)b * Tn * RS;
    float pcur = (float)rowbase[tid];   // pre[t=0]
    __syncthreads();

    const float4* __restrict__ hp4 = reinterpret_cast<const float4*>(hbuf);

    for (int t = 0; t < Tn; ++t) {
        // prefetch next step's pre element (row t+1; never the row written below)
        const int tn = (t + 1 < Tn) ? (t + 1) : t;
        const _Float16 pnext = rowbase[(size_t)tn * RS + tid];

        float a0 = pcur, a1 = 0.0f, a2 = 0.0f, a3 = 0.0f;
        #pragma unroll
        for (int i = 0; i < 32; ++i) {
            const float4 hv = hp4[i];
            a0 = dot2(bc2(hv.x), wreg[4 * i + 0], a0);
            a1 = dot2(bc2(hv.y), wreg[4 * i + 1], a1);
            a2 = dot2(bc2(hv.z), wreg[4 * i + 2], a2);
            a3 = dot2(bc2(hv.w), wreg[4 * i + 3], a3);
        }
        const float acc = (a0 + a1) + (a2 + a3);

        if (half) alpha_s[j] = fast_sigmoid(acc);
        __syncthreads();   // alpha ready; all hbuf reads of this step done

        if (!half) {
            const float cand  = fast_tanh(acc);
            const float alpha = alpha_s[j];
            const float hn = alpha * cand + (1.0f - alpha) * hprev;
            hprev = hn;
            if (writeF32) {
                outf[((size_t)b * Tn + t) * Hn + j] = hn;
            } else {
                rowbase[(size_t)t * RS + j] = (_Float16)hn;
            }
            hbuf[j] = (_Float16)hn;
        }
        __syncthreads();   // hbuf ready for next step
        pcur = (float)pnext;
    }

    if (!half) hfin[b * Hn + j] = hprev;
}

extern "C" void kernel_launch(void* const* d_in, const int* in_sizes, int n_in,
                              void* d_out, int out_size, void* d_ws, size_t ws_size,
                              hipStream_t stream) {
    const float* X    = (const float*)d_in[0];
    const float* Wih0 = (const float*)d_in[1];
    const float* Whh0 = (const float*)d_in[2];
    const float* bh0  = (const float*)d_in[3];
    const float* Wax0 = (const float*)d_in[4];
    const float* Wah0 = (const float*)d_in[5];
    const float* ba0  = (const float*)d_in[6];
    const float* Wih1 = (const float*)d_in[7];
    const float* Whh1 = (const float*)d_in[8];
    const float* bh1  = (const float*)d_in[9];
    const float* Wax1 = (const float*)d_in[10];
    const float* Wah1 = (const float*)d_in[11];
    const float* ba1  = (const float*)d_in[12];

    float* outf = (float*)d_out;
    float* hfin = outf + (size_t)Bn * Tn * Hn;
    _Float16* pre = (_Float16*)d_out;   // f16 view of the output region

    // K1: layer-0 input projections -> pre (f16, in d_out)
    gemm_x_kernel<<<dim3((Bn * Tn) / 64, 2), 256, 0, stream>>>(X, Wih0, bh0, Wax0, ba0, pre);
    // K2: layer-0 scan; h0 sequence (f16) written over consumed pre rows
    scan_kernel<<<dim3(Bn), 512, 0, stream>>>(pre, Whh0, Wah0, outf, hfin, 0);
    // K3: layer-1 input projections from h0 rows (in-place)
    gemm_h_kernel<<<dim3((Bn * Tn) / 32), 256, 0, stream>>>(pre, Wih1, bh1, Wax1, ba1);
    // K4: layer-1 scan; fp32 outputs written in place
    scan_kernel<<<dim3(Bn), 512, 0, stream>>>(pre, Whh1, Wah1, outf, hfin + Bn * Hn, 1);
}

// Round 3
// 4409.018 us; speedup vs baseline: 13.3199x; 1.0142x over previous
//
#include <hip/hip_runtime.h>

#define Bn 64
#define Tn 2048
#define In 128
#define Hn 256
#define RS 512  // row stride in f16 elements for pre/out rows (1024 B)

typedef _Float16 h2 __attribute__((ext_vector_type(2)));
typedef _Float16 f16x8 __attribute__((ext_vector_type(8)));
typedef float f32x4 __attribute__((ext_vector_type(4)));

__device__ __forceinline__ float fast_sigmoid(float x) {
    return 1.0f / (1.0f + __expf(-x));
}
__device__ __forceinline__ float fast_tanh(float x) {
    return 2.0f / (1.0f + __expf(-2.0f * x)) - 1.0f;
}
__device__ __forceinline__ h2 bc2(float f) {
    return __builtin_bit_cast(h2, f);
}

// ---------------------------------------------------------------------------
// K1: pre0[m][512] (f16, in d_out) = X[m][0:128] @ [Wih0 | Wax0] + [bh0 | ba0]
// ---------------------------------------------------------------------------
__global__ void gemm_x_kernel(const float* __restrict__ X,
                              const float* __restrict__ Wih0, const float* __restrict__ bh0,
                              const float* __restrict__ Wax0, const float* __restrict__ ba0,
                              _Float16* __restrict__ pre)
{
    __shared__ __align__(16) float Xs[64 * In];  // 32 KB
    const int m0 = blockIdx.x * 64;
    const int s  = blockIdx.y;
    const float* __restrict__ W    = s ? Wax0 : Wih0;
    const float* __restrict__ bias = s ? ba0  : bh0;

    {
        const float4* __restrict__ src = reinterpret_cast<const float4*>(X + (size_t)m0 * In);
        float4* __restrict__ dst = reinterpret_cast<float4*>(Xs);
        #pragma unroll
        for (int i = 0; i < 8; ++i) dst[threadIdx.x + 256 * i] = src[threadIdx.x + 256 * i];
    }
    __syncthreads();

    const int c  = threadIdx.x & 63;
    const int rg = threadIdx.x >> 6;
    const int mr = rg * 16;

    float acc[16][4];
    #pragma unroll
    for (int u = 0; u < 4; ++u) {
        const float bv = bias[c + 64 * u];
        #pragma unroll
        for (int r = 0; r < 16; ++r) acc[r][u] = bv;
    }

    const float4* __restrict__ Xs4 = reinterpret_cast<const float4*>(Xs);
    #pragma unroll 4
    for (int kc = 0; kc < 32; ++kc) {
        float wv[4][4];
        #pragma unroll
        for (int kk = 0; kk < 4; ++kk)
            #pragma unroll
            for (int u = 0; u < 4; ++u)
                wv[kk][u] = W[(size_t)(4 * kc + kk) * Hn + c + 64 * u];
        #pragma unroll
        for (int r = 0; r < 16; ++r) {
            const float4 xv = Xs4[(mr + r) * 32 + kc];
            #pragma unroll
            for (int u = 0; u < 4; ++u)
                acc[r][u] += xv.x * wv[0][u] + xv.y * wv[1][u] + xv.z * wv[2][u] + xv.w * wv[3][u];
        }
    }

    #pragma unroll
    for (int r = 0; r < 16; ++r)
        #pragma unroll
        for (int u = 0; u < 4; ++u)
            pre[(size_t)(m0 + mr + r) * RS + s * Hn + c + 64 * u] = (_Float16)acc[r][u];
}

// ---------------------------------------------------------------------------
// K3: pre1 (in-place over pre rows) = h0seq(f16) @ [Wih1 | Wax1] + bias
// ---------------------------------------------------------------------------
__global__ void gemm_h_kernel(_Float16* __restrict__ pre,
                              const float* __restrict__ Wih1, const float* __restrict__ bh1,
                              const float* __restrict__ Wax1, const float* __restrict__ ba1)
{
    __shared__ __align__(16) _Float16 Hs[32 * Hn];  // 16 KB
    const int m0 = blockIdx.x * 32;

    {
        float4* __restrict__ dst = reinterpret_cast<float4*>(Hs);
        #pragma unroll
        for (int q = 0; q < 4; ++q) {
            const int id  = threadIdx.x + 256 * q;
            const int row = id >> 5;
            const int off = id & 31;
            const float4* __restrict__ src =
                reinterpret_cast<const float4*>(pre + (size_t)(m0 + row) * RS);
            dst[row * 32 + off] = src[off];
        }
    }
    __syncthreads();

    const int c  = threadIdx.x & 63;
    const int rg = threadIdx.x >> 6;
    const int mr = rg * 8;

    const float* Wp[8];
    float acc[8][8];
    #pragma unroll
    for (int u = 0; u < 8; ++u) {
        const int colu = c + 64 * u;
        const float bv = (colu < Hn) ? bh1[colu] : ba1[colu - Hn];
        Wp[u] = (colu < Hn) ? (Wih1 + colu) : (Wax1 + (colu - Hn));
        #pragma unroll
        for (int r = 0; r < 8; ++r) acc[r][u] = bv;
    }

    const float2* __restrict__ Hs2 = reinterpret_cast<const float2*>(Hs);
    #pragma unroll 2
    for (int kc = 0; kc < 64; ++kc) {
        float wv[4][8];
        #pragma unroll
        for (int kk = 0; kk < 4; ++kk)
            #pragma unroll
            for (int u = 0; u < 8; ++u)
                wv[kk][u] = Wp[u][(size_t)(4 * kc + kk) * Hn];
        #pragma unroll
        for (int r = 0; r < 8; ++r) {
            const float2 q = Hs2[(mr + r) * 64 + kc];
            const h2 p0 = bc2(q.x), p1 = bc2(q.y);
            const float f0 = (float)p0.x, f1 = (float)p0.y, f2 = (float)p1.x, f3 = (float)p1.y;
            #pragma unroll
            for (int u = 0; u < 8; ++u)
                acc[r][u] += f0 * wv[0][u] + f1 * wv[1][u] + f2 * wv[2][u] + f3 * wv[3][u];
        }
    }

    #pragma unroll
    for (int r = 0; r < 8; ++r)
        #pragma unroll
        for (int u = 0; u < 8; ++u)
            pre[(size_t)(m0 + mr + r) * RS + c + 64 * u] = (_Float16)acc[r][u];
}

// ---------------------------------------------------------------------------
// MFMA scan. 64 blocks x 512 threads (8 waves). Wave w: matvec mv=w>>2
// (0=U,1=A), col-quarter nq=w&3. Weights resident in VGPRs as 32 B-fragments
// (f16). A-fragments: all 16 rows = h chunk (16-lane groups read same 16 B),
// so every D reg holds y[col]. y exchanged via LDS; 256 activation threads
// keep h_prev in registers; hbuf double-buffered; 2 barriers/step.
// ---------------------------------------------------------------------------
__global__ __launch_bounds__(512, 2)
void scan_mfma_kernel(_Float16* __restrict__ pre,
                      const float* __restrict__ WU, const float* __restrict__ WA,
                      float* __restrict__ outf, float* __restrict__ hfin, int writeF32)
{
    __shared__ __align__(16) _Float16 hbuf[2][Hn];   // 1 KB
    __shared__ __align__(8)  float    yua[Hn][2];    // 2 KB

    const int b    = blockIdx.x;
    const int tid  = threadIdx.x;
    const int lane = tid & 63;
    const int wv   = tid >> 6;       // wave id (uniform)
    const int mv   = wv >> 2;        // 0 = U (tanh), 1 = A (sigmoid)
    const int nq   = wv & 3;         // 64-col quarter
    const int g    = lane >> 4;      // k-subgroup within wave
    const int cl   = lane & 15;      // col within 16-tile

    // ---- B fragments (weights) resident in VGPRs: bfrag[kc][nt] ----
    const float* __restrict__ W = mv ? WA : WU;
    f16x8 bfrag[8][4];
    #pragma unroll
    for (int kc = 0; kc < 8; ++kc) {
        #pragma unroll
        for (int nt = 0; nt < 4; ++nt) {
            const int n  = 64 * nq + 16 * nt + cl;
            const int k0 = 32 * kc + 8 * g;
            f16x8 f;
            #pragma unroll
            for (int jj = 0; jj < 8; ++jj)
                f[jj] = (_Float16)W[(size_t)(k0 + jj) * Hn + n];
            bfrag[kc][nt] = f;
        }
    }

    _Float16* __restrict__ rowbase = pre + (size_t)b * Tn * RS;
    const int j = tid;               // activation column for tid < 256
    float hprev = 0.0f;
    float pU = 0.0f, pA = 0.0f;
    if (tid < Hn) {
        hbuf[0][tid] = (_Float16)0.0f;
        pU = (float)rowbase[j];
        pA = (float)rowbase[Hn + j];
    }
    __syncthreads();

    for (int t = 0; t < Tn; ++t) {
        // ---- A fragments from current h buffer ----
        const float4* __restrict__ hb =
            reinterpret_cast<const float4*>(&hbuf[t & 1][0]);
        f16x8 af[8];
        #pragma unroll
        for (int kc = 0; kc < 8; ++kc)
            af[kc] = __builtin_bit_cast(f16x8, hb[kc * 4 + g]);

        // ---- MFMA K-loop: 4 N-tiles x 8 K-chunks ----
        const f32x4 z = {0.0f, 0.0f, 0.0f, 0.0f};
        f32x4 a0 = __builtin_amdgcn_mfma_f32_16x16x32_f16(af[0], bfrag[0][0], z, 0, 0, 0);
        f32x4 a1 = __builtin_amdgcn_mfma_f32_16x16x32_f16(af[0], bfrag[0][1], z, 0, 0, 0);
        f32x4 a2 = __builtin_amdgcn_mfma_f32_16x16x32_f16(af[0], bfrag[0][2], z, 0, 0, 0);
        f32x4 a3 = __builtin_amdgcn_mfma_f32_16x16x32_f16(af[0], bfrag[0][3], z, 0, 0, 0);
        #pragma unroll
        for (int kc = 1; kc < 8; ++kc) {
            a0 = __builtin_amdgcn_mfma_f32_16x16x32_f16(af[kc], bfrag[kc][0], a0, 0, 0, 0);
            a1 = __builtin_amdgcn_mfma_f32_16x16x32_f16(af[kc], bfrag[kc][1], a1, 0, 0, 0);
            a2 = __builtin_amdgcn_mfma_f32_16x16x32_f16(af[kc], bfrag[kc][2], a2, 0, 0, 0);
            a3 = __builtin_amdgcn_mfma_f32_16x16x32_f16(af[kc], bfrag[kc][3], a3, 0, 0, 0);
        }

        // ---- prefetch next step's pre-activation row (consumed post-barrier
        //      next step; __syncthreads drains vmcnt, so no in-place race) ----
        float pUn = 0.0f, pAn = 0.0f;
        {
            const int tn = (t + 1 < Tn) ? (t + 1) : t;
            if (tid < Hn) {
                pUn = (float)rowbase[(size_t)tn * RS + j];
                pAn = (float)rowbase[(size_t)tn * RS + Hn + j];
            }
        }

        // ---- publish y: lane holds y[64*nq + 16*g + cl] in acc[g] (rows
        //      identical -> any component); linear addr = conflict-free ----
        const float yv = (g == 0) ? a0.x : (g == 1) ? a1.x : (g == 2) ? a2.x : a3.x;
        yua[64 * nq + lane][mv] = yv;
        __syncthreads();   // y ready; h reads of this step done

        if (tid < Hn) {
            const float yU = yua[j][0] + pU;
            const float yA = yua[j][1] + pA;
            const float cand  = fast_tanh(yU);
            const float alpha = fast_sigmoid(yA);
            const float hn = alpha * cand + (1.0f - alpha) * hprev;
            hprev = hn;
            hbuf[(t + 1) & 1][j] = (_Float16)hn;
            if (writeF32) {
                outf[((size_t)b * Tn + t) * Hn + j] = hn;
            } else {
                rowbase[(size_t)t * RS + j] = (_Float16)hn;
            }
        }
        __syncthreads();   // hbuf[(t+1)&1] ready for next step
        pU = pUn; pA = pAn;
    }

    if (tid < Hn) hfin[b * Hn + j] = hprev;
}

extern "C" void kernel_launch(void* const* d_in, const int* in_sizes, int n_in,
                              void* d_out, int out_size, void* d_ws, size_t ws_size,
                              hipStream_t stream) {
    const float* X    = (const float*)d_in[0];
    const float* Wih0 = (const float*)d_in[1];
    const float* Whh0 = (const float*)d_in[2];
    const float* bh0  = (const float*)d_in[3];
    const float* Wax0 = (const float*)d_in[4];
    const float* Wah0 = (const float*)d_in[5];
    const float* ba0  = (const float*)d_in[6];
    const float* Wih1 = (const float*)d_in[7];
    const float* Whh1 = (const float*)d_in[8];
    const float* bh1  = (const float*)d_in[9];
    const float* Wax1 = (const float*)d_in[10];
    const float* Wah1 = (const float*)d_in[11];
    const float* ba1  = (const float*)d_in[12];

    float* outf = (float*)d_out;
    float* hfin = outf + (size_t)Bn * Tn * Hn;
    _Float16* pre = (_Float16*)d_out;

    gemm_x_kernel<<<dim3((Bn * Tn) / 64, 2), 256, 0, stream>>>(X, Wih0, bh0, Wax0, ba0, pre);
    scan_mfma_kernel<<<dim3(Bn), 512, 0, stream>>>(pre, Whh0, Wah0, outf, hfin, 0);
    gemm_h_kernel<<<dim3((Bn * Tn) / 32), 256, 0, stream>>>(pre, Wih1, bh1, Wax1, ba1);
    scan_mfma_kernel<<<dim3(Bn), 512, 0, stream>>>(pre, Whh1, Wah1, outf, hfin + Bn * Hn, 1);
}